// Round 14
// baseline (12432.983 us; speedup 1.0000x reference)
//
#include <hip/hip_runtime.h>
#include <hip/hip_bf16.h>
#include <cstdint>
#include <cstddef>

#define Bdim 256
#define Tdim 256
#define Idim 512
#define Hdim 1024
#define Odim 5
#define BH (Bdim * Hdim)
#define BI (Bdim * Idim)
#define KLDS 1280
#define ABASE 81920   // byte offset of granule bufs (W-LDS is [0,81920))

using short8 = __attribute__((ext_vector_type(8))) short;
using f32x4  = __attribute__((ext_vector_type(4))) float;
typedef unsigned long long u64;

__device__ __forceinline__ short bf16_of(float f) {
  unsigned u = __builtin_bit_cast(unsigned, f);
  u += 0x7fffu + ((u >> 16) & 1u);
  return (short)(u >> 16);
}

__device__ __forceinline__ float sigmf(float x) {
  return 1.0f / (1.0f + __expf(-x));
}

__global__ __launch_bounds__(256) void k_cvt_bf16(const float* __restrict__ src,
                                                  short* __restrict__ dst, int n) {
  int i0 = (blockIdx.x * 256 + threadIdx.x) * 8;
  int stride = gridDim.x * 256 * 8;
  for (int i = i0; i < n; i += stride) {
    float4 u = *reinterpret_cast<const float4*>(src + i);
    float4 v = *reinterpret_cast<const float4*>(src + i + 4);
    short8 o = {bf16_of(u.x), bf16_of(u.y), bf16_of(u.z), bf16_of(u.w),
                bf16_of(v.x), bf16_of(v.y), bf16_of(v.z), bf16_of(v.w)};
    *reinterpret_cast<short8*>(dst + i) = o;
  }
}

// x fp32 [B][T][I] -> bf16 [T][B][I]
__global__ __launch_bounds__(256) void k_cvt_x(const float* __restrict__ src,
                                               short* __restrict__ dst) {
  int e = (blockIdx.x * 256 + threadIdx.x) * 8;
  int row = e >> 9;
  int i0  = e & 511;
  int b = row >> 8, t = row & 255;
  float4 u = *reinterpret_cast<const float4*>(src + e);
  float4 v = *reinterpret_cast<const float4*>(src + e + 4);
  short8 o = {bf16_of(u.x), bf16_of(u.y), bf16_of(u.z), bf16_of(u.w),
              bf16_of(v.x), bf16_of(v.y), bf16_of(v.z), bf16_of(v.w)};
  *reinterpret_cast<short8*>(dst + (((t << 8) + b) << 9) + i0) = o;
}

__global__ __launch_bounds__(256) void k_init(const float* __restrict__ hidden,
    short* __restrict__ h0s0, short* __restrict__ h1s0) {
  int i = blockIdx.x * 256 + threadIdx.x;
  if (i < BH) {
    h0s0[i] = bf16_of(hidden[i]);
    h1s0[i] = bf16_of(hidden[2 * BH + i]);
  }
}

__device__ __forceinline__ void ctr_arrive(unsigned* ctr, int c) {
  __builtin_amdgcn_sched_barrier(0);
  __syncthreads();   // drains vmcnt(0): all agent-scope h-stores at MALL
  if (threadIdx.x == 0)
    __hip_atomic_fetch_add(&ctr[c * 32], 1u, __ATOMIC_RELAXED,
                           __HIP_MEMORY_SCOPE_AGENT);
}

__device__ __forceinline__ void poll_wave(unsigned* ctr, unsigned tg0,
                                          unsigned tg1, int lane) {
  const unsigned tgt = (lane < 8) ? tg0 : (lane < 16 ? tg1 : 0u);
  unsigned* p = ctr + (lane & 15) * 32;
  for (;;) {
    bool ok = true;
    if (tgt) {
      unsigned v = __hip_atomic_load(p, __ATOMIC_RELAXED, __HIP_MEMORY_SCOPE_AGENT);
      ok = (v >= tgt);
    }
    if (__all(ok)) break;
    __builtin_amdgcn_s_sleep(1);
  }
}

#define WAITV(N) do { asm volatile("s_waitcnt vmcnt(" #N ")" ::: "memory");    \
                      __builtin_amdgcn_sched_barrier(0); } while (0)
#define SBAR()   asm volatile("s_barrier" ::: "memory")

#define MF(M,N,A,B) acc[M][N] = __builtin_amdgcn_mfma_f32_16x16x32_bf16(A, B, acc[M][N], 0, 0, 0)

// A reads (granule buf BB): linear [4 kb][256 row][8]; balanced b128 banks.
#define AREADS(BB)                                                             \
    const int _bo = ABASE + (BB) * 16384;                                      \
    short8 a0 = *(const short8*)((char*)lw + _bo + ((rg*256 + wv*64 +  0 + col) << 4)); \
    short8 a1 = *(const short8*)((char*)lw + _bo + ((rg*256 + wv*64 + 16 + col) << 4)); \
    short8 a2 = *(const short8*)((char*)lw + _bo + ((rg*256 + wv*64 + 32 + col) << 4)); \
    short8 a3 = *(const short8*)((char*)lw + _bo + ((rg*256 + wv*64 + 48 + col) << 4));

// B from swizzled W-LDS (k-step KS < 40)
#define COMP_L(KS, BB) {                                                       \
    AREADS(BB)                                                                 \
    short8 b0 = *(const short8*)((char*)lw + (      col) * 2560 + (((KS)*64 + rg*16) ^ xmask)); \
    short8 b1 = *(const short8*)((char*)lw + (16 +  col) * 2560 + (((KS)*64 + rg*16) ^ xmask)); \
    MF(0,0,a0,b0); MF(1,0,a1,b0); MF(2,0,a2,b0); MF(3,0,a3,b0);                \
    MF(0,1,a0,b1); MF(1,1,a1,b1); MF(2,1,a2,b1); MF(3,1,a3,b1); }

// B from prefetched registers (tail k-steps)
#define COMP_R(BB, B0, B1) {                                                   \
    AREADS(BB)                                                                 \
    MF(0,0,a0,B0); MF(1,0,a1,B0); MF(2,0,a2,B0); MF(3,0,a3,B0);                \
    MF(0,1,a0,B1); MF(1,1,a1,B1); MF(2,1,a2,B1); MF(3,1,a3,B1); }

// prefetch one 4-granule chunk of tail-B frags into regs (compile-time idx)
#define PREF(BUF, GB) { _Pragma("unroll")                                      \
    for (int q = 0; q < 4; ++q) {                                              \
      BUF[q][0] = *(const short8*)(wrow0g + ((GB) + q) * 32 + rg * 8);         \
      BUF[q][1] = *(const short8*)(wrow1g + ((GB) + q) * 32 + rg * 8);         \
    } }

#define ITER_L(G, WN) { WAITV(WN); SBAR(); COMP_L(G, (G) % 3); SBAR();         \
                        if ((G) + 3 < NG) stage_g((G) + 3); }
#define ITER_R(G, WN, B0, B1) { WAITV(WN); SBAR(); COMP_R((G) % 3, B0, B1);    \
                        SBAR(); if ((G) + 3 < NG) stage_g((G) + 3); }

// Persistent LSTM: 256 WGs x 256 thr (4 waves = batch quarters), 1 WG/CU.
// WG = (layer, hslice of 8 hcols -> 32 weight rows). Weights: LDS [32][1280]
// (XOR-swizzled); tail k>=1280 register-prefetched from L2-hot global.
// A (full 256-batch): global_load_lds granules (32k x 256b = 16KB), 3-buf.
__global__ __launch_bounds__(256, 1) void k_persist(
    const short* __restrict__ W0b,    // [4H][1536] bf16
    const short* __restrict__ W1b,    // [4H][2048] bf16
    const float* __restrict__ b0v, const float* __restrict__ b1v,
    const float* __restrict__ hidden,
    const float* __restrict__ xf,     // fp32 [B][T][I] (fallback)
    const short* __restrict__ xbt,    // bf16 [T][B][I] (preferred)
    int useXb,
    short* __restrict__ h0seq, short* __restrict__ h1seq,  // [D][B][H]
    float* __restrict__ finals,       // [L][2][B][H] fp32 (in d_out)
    unsigned* __restrict__ ctr, int D) {
  extern __shared__ short lw[];
  float* gfp = (float*)((char*)lw + ABASE);   // [4 gate][8 hc][260] f32, alias
  const int tid  = threadIdx.x;
  const int wg   = blockIdx.x;
  const bool isL0 = (wg < 128);
  const int hsl   = isL0 ? wg : wg - 128;
  const int hcol0 = hsl * 8;
  const int K     = isL0 ? (Hdim + Idim) : (2 * Hdim);
  const int layer = isL0 ? 0 : 1;
  const int myc   = layer * 8 + (wg & 7);
  const int lead  = D - 2;
  const int NG    = isL0 ? (useXb ? 48 : 32) : 64;
  const short* Wb = isL0 ? W0b : W1b;
  const float* bsrc = isL0 ? b0v : b1v;

  const int lane = tid & 63;
  const int wv   = tid >> 6;          // wave = batch quarter (rows wv*64..+64)
  const int col  = lane & 15;
  const int rg   = lane >> 4;
  const int xmask = (col & 7) << 4;

  // global W rows for this lane's two N-tiles (tile0={f,i}, tile1={g,o})
  const short* wrow0g = Wb + (size_t)(((col >= 8) ? 1 : 0) * Hdim + hcol0 + (col & 7)) * K;
  const short* wrow1g = Wb + (size_t)((2 + ((col >= 8) ? 1 : 0)) * Hdim + hcol0 + (col & 7)) * K;

  // ---- W-LDS init: [32 rows][1280 k] packed, XOR-swizzled by row&7 ----
  for (int idx = tid; idx < 32 * 160; idx += 256) {
    int rr = idx / 160, c8 = idx - rr * 160;
    short8 v = *(const short8*)(Wb + (size_t)((rr >> 3) * Hdim + hcol0 + (rr & 7)) * K + c8 * 8);
    *(short8*)((char*)lw + rr * 2560 + ((c8 * 16) ^ ((rr & 7) << 4))) = v;
  }

  float biasv[2];
  #pragma unroll
  for (int n = 0; n < 2; ++n)
    biasv[n] = bsrc[(n * 2 + (col >= 8 ? 1 : 0)) * Hdim + hcol0 + (col & 7)];

  // recombine state: thread t owns batch row t, hcols hcol0..+8
  float creg[8], hfin[8];
  { const float* cs = hidden + (size_t)(layer * 2 + 1) * BH + (size_t)tid * Hdim + hcol0;
    #pragma unroll
    for (int e = 0; e < 8; ++e) { creg[e] = cs[e]; hfin[e] = 0.f; } }

  if (tid == 0)
    (void)__hip_atomic_load(ctr, __ATOMIC_ACQUIRE, __HIP_MEMORY_SCOPE_AGENT);
  __syncthreads();

  int i_cur = 0;
  for (int r = 0; r < 256; ++r) {
    const int i_next = (i_cur + 1 == D) ? 0 : i_cur + 1;

    // ---- sync (per-wave poll; wrap-inv before any staged reads) ----
    if (isL0) {
      unsigned tg1 = (r > lead) ? 16u * (unsigned)(r - lead) : 0u;
      if (r > 0 || tg1) poll_wave(ctr, (r > 0) ? 16u * (unsigned)r : 0u, tg1, lane);
    } else {
      poll_wave(ctr, 16u * (unsigned)(r + 1), (r > 0) ? 16u * (unsigned)r : 0u, lane);
    }
    if (lane == 0 && r > 0 && (i_cur == 0 || i_next == 0))
      (void)__hip_atomic_load(ctr, __ATOMIC_ACQUIRE, __HIP_MEMORY_SCOPE_AGENT);

    const short* hb = (isL0 ? h0seq + (size_t)i_cur * BH : h1seq + (size_t)i_cur * BH);
    const short* xb = isL0 ? (useXb ? xbt + (size_t)r * BI : (const short*)nullptr)
                           : h0seq + (size_t)i_next * BH;

    auto stage_g = [&](int g) {
      const short* s; int rs;
      if (g < 32) { s = hb + g * 32; rs = Hdim; }
      else if (isL0) { s = xb + (g * 32 - 1024); rs = Idim; }
      else { s = xb + (g - 32) * 32; rs = Hdim; }
      char* db = (char*)lw + ABASE + (g % 3) * 16384 + ((wv * 64) << 4);
      #pragma unroll
      for (int kb = 0; kb < 4; ++kb)
        __builtin_amdgcn_global_load_lds(
          (const __attribute__((address_space(1))) unsigned*)(const void*)
            (s + (size_t)(wv * 64 + lane) * rs + kb * 8),
          (__attribute__((address_space(3))) unsigned*)(void*)(db + (kb << 12)),
          16, 0, 0);
    };

    f32x4 acc[4][2] = {};
    short8 bt0[4][2], bt1[4][2];

    if (NG > 40) PREF(bt0, 40)          // tail chunk0, issued before stages
    stage_g(0); stage_g(1); stage_g(2);

    if (NG == 32) {                     // L0 fallback: h-granules only
      for (int g = 0; g < 30; ++g) ITER_L(g, 8);
      ITER_L(30, 4); ITER_L(31, 0);
      // fp32-x region: k-steps 32..47, B from LDS (ks<40) or global (ks>=40)
      const float* xr[4];
      #pragma unroll
      for (int m = 0; m < 4; ++m)
        xr[m] = xf + ((size_t)(wv * 64 + m * 16 + col) * Tdim + r) * Idim + rg * 8;
      #pragma unroll
      for (int ks = 32; ks < 48; ++ks) {
        short8 b0, b1;
        if (ks < 40) {
          b0 = *(const short8*)((char*)lw + (     col) * 2560 + ((ks * 64 + rg * 16) ^ xmask));
          b1 = *(const short8*)((char*)lw + (16 + col) * 2560 + ((ks * 64 + rg * 16) ^ xmask));
        } else {
          b0 = *(const short8*)(wrow0g + ks * 32 + rg * 8);
          b1 = *(const short8*)(wrow1g + ks * 32 + rg * 8);
        }
        #pragma unroll
        for (int m = 0; m < 4; ++m) {
          const float* p = xr[m] + (ks - 32) * 32;
          f32x4 u = *(const f32x4*)p, v = *(const f32x4*)(p + 4);
          short8 a = {bf16_of(u[0]), bf16_of(u[1]), bf16_of(u[2]), bf16_of(u[3]),
                      bf16_of(v[0]), bf16_of(v[1]), bf16_of(v[2]), bf16_of(v[3])};
          MF(m, 0, a, b0); MF(m, 1, a, b1);
        }
      }
    } else {
      for (int g = 0; g < 40; ++g) ITER_L(g, 8);
      if (isL0) {                       // NG=48: tail 40..47 (2 chunks)
        PREF(bt1, 44)
        ITER_R(40, 16, bt0[0][0], bt0[0][1]); ITER_R(41, 16, bt0[1][0], bt0[1][1]);
        ITER_R(42, 16, bt0[2][0], bt0[2][1]); ITER_R(43,  8, bt0[3][0], bt0[3][1]);
        ITER_R(44, 12, bt1[0][0], bt1[0][1]); ITER_R(45,  8, bt1[1][0], bt1[1][1]);
        ITER_R(46,  4, bt1[2][0], bt1[2][1]); ITER_R(47,  0, bt1[3][0], bt1[3][1]);
      } else {                          // NG=64: tail 40..63 (6 chunks)
        PREF(bt1, 44)
        ITER_R(40, 16, bt0[0][0], bt0[0][1]); ITER_R(41, 16, bt0[1][0], bt0[1][1]);
        ITER_R(42, 16, bt0[2][0], bt0[2][1]); ITER_R(43,  8, bt0[3][0], bt0[3][1]);
        PREF(bt0, 48)
        ITER_R(44, 16, bt1[0][0], bt1[0][1]); ITER_R(45, 16, bt1[1][0], bt1[1][1]);
        ITER_R(46, 16, bt1[2][0], bt1[2][1]); ITER_R(47,  8, bt1[3][0], bt1[3][1]);
        PREF(bt1, 52)
        ITER_R(48, 16, bt0[0][0], bt0[0][1]); ITER_R(49, 16, bt0[1][0], bt0[1][1]);
        ITER_R(50, 16, bt0[2][0], bt0[2][1]); ITER_R(51,  8, bt0[3][0], bt0[3][1]);
        PREF(bt0, 56)
        ITER_R(52, 16, bt1[0][0], bt1[0][1]); ITER_R(53, 16, bt1[1][0], bt1[1][1]);
        ITER_R(54, 16, bt1[2][0], bt1[2][1]); ITER_R(55,  8, bt1[3][0], bt1[3][1]);
        PREF(bt1, 60)
        ITER_R(56, 16, bt0[0][0], bt0[0][1]); ITER_R(57, 16, bt0[1][0], bt0[1][1]);
        ITER_R(58, 16, bt0[2][0], bt0[2][1]); ITER_R(59,  8, bt0[3][0], bt0[3][1]);
        ITER_R(60, 12, bt1[0][0], bt1[0][1]); ITER_R(61,  8, bt1[1][0], bt1[1][1]);
        ITER_R(62,  4, bt1[2][0], bt1[2][1]); ITER_R(63,  0, bt1[3][0], bt1[3][1]);
      }
    }

    // ---- gate staging into gf (aliases bufs; all DMA/reads done) ----
    #pragma unroll
    for (int m = 0; m < 4; ++m)
      #pragma unroll
      for (int n = 0; n < 2; ++n) {
        f32x4 v = acc[m][n];
        float b = biasv[n];
        v[0] += b; v[1] += b; v[2] += b; v[3] += b;
        *(f32x4*)(gfp + ((n * 2 + (col >= 8 ? 1 : 0)) * 8 + (col & 7)) * 260
                      + wv * 64 + m * 16 + rg * 4) = v;
      }
    __syncthreads();

    // ---- recombine: thread t = batch row t ----
    {
      float fv[8], iv[8], gv[8], ov[8];
      #pragma unroll
      for (int e = 0; e < 8; ++e) {
        fv[e] = gfp[(0 * 8 + e) * 260 + tid];
        iv[e] = gfp[(1 * 8 + e) * 260 + tid];
        gv[e] = gfp[(2 * 8 + e) * 260 + tid];
        ov[e] = gfp[(3 * 8 + e) * 260 + tid];
      }
      unsigned short hb16[8];
      #pragma unroll
      for (int e = 0; e < 8; ++e) {
        float f_ = sigmf(fv[e]), i_ = sigmf(iv[e]);
        float g_ = tanhf(gv[e]), o_ = sigmf(ov[e]);
        float cn = f_ * creg[e] + i_ * g_;
        creg[e] = cn;
        float hn = o_ * tanhf(cn);
        hfin[e] = hn;
        hb16[e] = (unsigned short)bf16_of(hn);
      }
      short* hout = (isL0 ? h0seq : h1seq) + (size_t)i_next * BH
                    + (size_t)tid * Hdim + hcol0;
      u64 plo = (u64)hb16[0] | ((u64)hb16[1] << 16) | ((u64)hb16[2] << 32) | ((u64)hb16[3] << 48);
      u64 phi = (u64)hb16[4] | ((u64)hb16[5] << 16) | ((u64)hb16[6] << 32) | ((u64)hb16[7] << 48);
      __hip_atomic_store((u64*)hout, plo, __ATOMIC_RELAXED, __HIP_MEMORY_SCOPE_AGENT);
      __hip_atomic_store((u64*)(hout + 4), phi, __ATOMIC_RELAXED, __HIP_MEMORY_SCOPE_AGENT);
    }
    ctr_arrive(ctr, myc);
    i_cur = i_next;
  }

  // ---- epilogue: finals [L][2][B][H] ----
  {
    float* fh = finals + (size_t)(layer * 2) * BH + (size_t)tid * Hdim + hcol0;
    float* fc = fh + BH;
    *(float4*)fh = make_float4(hfin[0], hfin[1], hfin[2], hfin[3]);
    *(float4*)(fh + 4) = make_float4(hfin[4], hfin[5], hfin[6], hfin[7]);
    *(float4*)fc = make_float4(creg[0], creg[1], creg[2], creg[3]);
    *(float4*)(fc + 4) = make_float4(creg[4], creg[5], creg[6], creg[7]);
  }
}

__global__ __launch_bounds__(256) void k_outproj(const float* __restrict__ h1f,
    const float* __restrict__ Wout, const float* __restrict__ bout,
    float* __restrict__ out) {
  int b = blockIdx.x;
  int tid = threadIdx.x;
  float hv[4];
  #pragma unroll
  for (int j = 0; j < 4; ++j) hv[j] = h1f[b * Hdim + tid + j * 256];
  __shared__ float red[Odim][4];
  #pragma unroll
  for (int o = 0; o < Odim; ++o) {
    float p = 0.f;
    #pragma unroll
    for (int j = 0; j < 4; ++j) p += hv[j] * Wout[o * Hdim + tid + j * 256];
    #pragma unroll
    for (int s = 32; s > 0; s >>= 1) p += __shfl_down(p, s, 64);
    if ((tid & 63) == 0) red[o][tid >> 6] = p;
  }
  __syncthreads();
  if (tid < Odim)
    out[b * Odim + tid] = red[tid][0] + red[tid][1] + red[tid][2] + red[tid][3] + bout[tid];
}

extern "C" void kernel_launch(void* const* d_in, const int* in_sizes, int n_in,
                              void* d_out, int out_size, void* d_ws, size_t ws_size,
                              hipStream_t stream) {
  const float* x      = (const float*)d_in[0];
  const float* hidden = (const float*)d_in[1];
  const float* W0     = (const float*)d_in[2];
  const float* b0     = (const float*)d_in[3];
  const float* W1     = (const float*)d_in[4];
  const float* b1     = (const float*)d_in[5];
  const float* Wout   = (const float*)d_in[6];
  const float* bout   = (const float*)d_in[7];
  float* out = (float*)d_out;
  float* finals = out + Bdim * Odim;

  char* ws = (char*)d_ws;
  size_t off = 0;
  auto alloc = [&](size_t bytes) {
    void* p = ws + off;
    off += (bytes + 255) & ~(size_t)255;
    return p;
  };
  unsigned* ctr = (unsigned*)alloc(16 * 32 * sizeof(unsigned));
  short* W0b = (short*)alloc((size_t)4096 * 1536 * 2);
  short* W1b = (short*)alloc((size_t)4096 * 2048 * 2);
  const size_t seqSlot = (size_t)BH * 2;                     // 0.5 MB
  const size_t xbBytes = (size_t)Tdim * Bdim * Idim * 2;     // 67.1 MB
  int useXb = 0;
  short* xbt = nullptr;
  if (ws_size > off + xbBytes + 8 * 2 * seqSlot + (1 << 20)) {
    useXb = 1;
    xbt = (short*)alloc(xbBytes);
  }
  size_t avail = (ws_size > off + 512) ? (ws_size - off - 512) : 0;
  int D = (int)(avail / (2 * seqSlot));
  if (D > 64) D = 64;
  if (D < 4) D = 4;
  short* h0seq = (short*)alloc((size_t)D * seqSlot);
  short* h1seq = (short*)alloc((size_t)D * seqSlot);

  k_cvt_bf16<<<2048, 256, 0, stream>>>(W0, W0b, 4096 * 1536);
  k_cvt_bf16<<<2048, 256, 0, stream>>>(W1, W1b, 4096 * 2048);
  if (useXb)
    k_cvt_x<<<(Tdim * Bdim * Idim) / (256 * 8), 256, 0, stream>>>(x, xbt);
  k_init<<<BH / 256, 256, 0, stream>>>(hidden, h0seq, h1seq);
  hipMemsetAsync(ctr, 0, 16 * 32 * sizeof(unsigned), stream);

  const int ldsBytes = 131072;  // 80KB W + 48KB granule bufs (gf aliased)
  hipFuncSetAttribute((const void*)k_persist,
                      hipFuncAttributeMaxDynamicSharedMemorySize, ldsBytes);
  void* args[] = {(void*)&W0b, (void*)&W1b, (void*)&b0, (void*)&b1,
                  (void*)&hidden, (void*)&x, (void*)&xbt, (void*)&useXb,
                  (void*)&h0seq, (void*)&h1seq,
                  (void*)&finals, (void*)&ctr, (void*)&D};
  hipError_t ce = hipLaunchCooperativeKernel((const void*)k_persist,
                                             dim3(256), dim3(256),
                                             args, ldsBytes, stream);
  if (ce != hipSuccess) {
    k_persist<<<dim3(256), dim3(256), ldsBytes, stream>>>(
        W0b, W1b, b0, b1, hidden, x, xbt, useXb,
        h0seq, h1seq, finals, ctr, D);
  }

  k_outproj<<<Bdim, 256, 0, stream>>>(finals + 2 * BH, Wout, bout, out);
}